// Round 20
// baseline (630.400 us; speedup 1.0000x reference)
//
#include <hip/hip_runtime.h>
#include <math.h>

typedef short short8 __attribute__((ext_vector_type(8)));
typedef float f32x16 __attribute__((ext_vector_type(16)));

__device__ __forceinline__ unsigned short f2bf(float f) {
  unsigned u = __float_as_uint(f);
  unsigned r = u + 0x7fffu + ((u >> 16) & 1u);
  return (unsigned short)(r >> 16);
}
__device__ __forceinline__ float bf2f(unsigned short s) {
  return __uint_as_float(((unsigned)s) << 16);
}
__device__ __forceinline__ void gload_lds16(const void* g, void* l) {
  __builtin_amdgcn_global_load_lds(
      (const __attribute__((address_space(1))) unsigned int*)g,
      (__attribute__((address_space(3))) unsigned int*)l, 16, 0, 0);
}

#define TM 128
#define TN 128
#define GH 7  // y-tiles grouped per rasterization column (L2 locality)

// NT MFMA GEMM. NPROD=3: 2-plane split, TK=32. NPROD=1: 1-plane, TK=64
// (32KB LDS either way -> 5 blocks/CU at launch_bounds(256,5); the extra
// resident block overlaps the per-K-step vmcnt drain).
// 1D grid = GX*GY*GZ blocks (divisible by 8), XCD-chunked + grouped raster.
// MODE: 0=XC(h only) 1=QK(h only) 2=S(bf16) 3=OUT(+residual) 6=V-direct[c][n]
template<int MODE, int NPROD>
__global__ __launch_bounds__(256, 5) void mfma_gemm(
    const unsigned short* __restrict__ A0, const unsigned short* __restrict__ A1,
    const unsigned short* __restrict__ B0, const unsigned short* __restrict__ B1,
    int GX, int GY,
    int M, int N, int K, int ldA, int ldB, long sA, long sB,
    const float* __restrict__ bias, float alpha,
    float* __restrict__ outF, long sOutF,
    unsigned short* __restrict__ P0, long sP,
    unsigned short* __restrict__ R0, long sR,
    unsigned short* __restrict__ V0, long sV,
    const unsigned short* __restrict__ xcn, long sXcn)
{
  constexpr int NPL = (NPROD == 3) ? 2 : 1;
  constexpr int TKe = (NPROD == 1) ? 64 : 32;  // K-step
  constexpr int KK = TKe / 16;                 // MFMA sub-steps
  constexpr int NISS = TKe / 16;               // staging issues per matrix
  constexpr int SLOTS = TKe / 8;               // 16B slots per row
  __shared__ __align__(16) unsigned short As[NPL][128 * TKe];
  __shared__ __align__(16) unsigned short Bs[NPL][128 * TKe];

  const int tid = threadIdx.x;

  // ---- XCD-chunked bijective remap (total % 8 == 0) + grouped raster decode
  const int total = GX * GY * ((int)gridDim.x / (GX * GY));
  const int q = total >> 3;
  const int wg = blockIdx.x;
  const int c = (wg & 7) * q + (wg >> 3);
  const int pb = GX * GY;
  const int bz = c / pb;
  int r = c - bz * pb;
  const int gy = r / (GH * GX);
  int rr = r - gy * (GH * GX);
  const int hh = min(GH, GY - gy * GH);
  const int xt = rr / hh;
  const int yt = gy * GH + (rr - xt * hh);

  const int m0 = yt * TM, n0 = xt * TN;
  const int lane = tid & 63, w = tid >> 6;
  const int wm = w >> 1, wn = w & 1;
  const int g = lane >> 5, lr = lane & 31;

  // staging: issue i covers rows i*(256/SLOTS) + tid/SLOTS, slot tid%SLOTS;
  // source pre-swizzled so LDS slot s of row r holds k-chunk s ^ swz(r)
  const int strow = tid / SLOTS, stslot = tid % SLOTS;
  long aoff[NISS], boff[NISS];
#pragma unroll
  for (int i = 0; i < NISS; i++) {
    const int rw = i * (256 / SLOTS) + strow;
    const int sw = (TKe == 64) ? (stslot ^ (rw & 7)) : (stslot ^ ((rw >> 1) & 3));
    aoff[i] = (long)min(m0 + rw, M - 1) * ldA + sw * 8;
    boff[i] = (long)min(n0 + rw, N - 1) * ldB + sw * 8;
  }
  const unsigned short* Ap[2];
  const unsigned short* Bp[2];
  Ap[0] = A0 + bz * sA;
  Bp[0] = B0 + bz * sB;
  Ap[1] = (NPL == 2) ? A1 + bz * sA : Ap[0];
  Bp[1] = (NPL == 2) ? B1 + bz * sB : Bp[0];

  f32x16 acc[2][2];
#pragma unroll
  for (int i = 0; i < 2; i++)
#pragma unroll
    for (int j = 0; j < 2; j++)
#pragma unroll
      for (int e = 0; e < 16; e++) acc[i][j][e] = 0.f;

  const int NT = K / TKe;

  for (int kt = 0; kt < NT; kt++) {
    const long k0 = (long)kt * TKe;
    if (kt) __syncthreads();  // previous compute done before overwrite
#pragma unroll
    for (int p = 0; p < NPL; p++)
#pragma unroll
      for (int i = 0; i < NISS; i++) {
        gload_lds16(Ap[p] + aoff[i] + k0, (char*)&As[p][0] + i * 4096 + tid * 16);
        gload_lds16(Bp[p] + boff[i] + k0, (char*)&Bs[p][0] + i * 4096 + tid * 16);
      }
    __syncthreads();  // drain staging; other resident blocks compute meanwhile

#pragma unroll
    for (int kk = 0; kk < KK; kk++) {
      short8 af[2][NPL], bf[2][NPL];
#pragma unroll
      for (int i = 0; i < 2; i++) {
        const int rowa = wm * 64 + i * 32 + lr;
        const int sla = (TKe == 64) ? (((kk * 2 + g) ^ (rowa & 7)) * 8)
                                    : (((kk * 2 + g) ^ ((rowa >> 1) & 3)) * 8);
#pragma unroll
        for (int p = 0; p < NPL; p++)
          af[i][p] = *(const short8*)&As[p][rowa * TKe + sla];
        const int rowb = wn * 64 + i * 32 + lr;
        const int slb = (TKe == 64) ? (((kk * 2 + g) ^ (rowb & 7)) * 8)
                                    : (((kk * 2 + g) ^ ((rowb >> 1) & 3)) * 8);
#pragma unroll
        for (int p = 0; p < NPL; p++)
          bf[i][p] = *(const short8*)&Bs[p][rowb * TKe + slb];
      }
      __builtin_amdgcn_s_setprio(1);
#pragma unroll
      for (int i = 0; i < 2; i++)
#pragma unroll
        for (int j = 0; j < 2; j++) {
          acc[i][j] = __builtin_amdgcn_mfma_f32_32x32x16_bf16(af[i][0], bf[j][0], acc[i][j], 0, 0, 0);
          if (NPROD == 3) {
            acc[i][j] = __builtin_amdgcn_mfma_f32_32x32x16_bf16(af[i][0], bf[j][1], acc[i][j], 0, 0, 0);
            acc[i][j] = __builtin_amdgcn_mfma_f32_32x32x16_bf16(af[i][1], bf[j][0], acc[i][j], 0, 0, 0);
          }
        }
      __builtin_amdgcn_s_setprio(0);
    }
  }

  // epilogue: row = m0+wm*64+i*32 + rq*8 + g*4 + t ; col = n0+wn*64+j*32+lr
#pragma unroll
  for (int i = 0; i < 2; i++)
#pragma unroll
    for (int j = 0; j < 2; j++) {
      const int cb = n0 + wn * 64 + j * 32;
      const int col = cb + lr;
#pragma unroll
      for (int rq = 0; rq < 4; rq++)
#pragma unroll
        for (int t = 0; t < 4; t++) {
          const int reg = rq * 4 + t;
          const int row = m0 + wm * 64 + i * 32 + rq * 8 + g * 4 + t;
          float v = acc[i][j][reg];
          if (MODE == 0) {  // XC: relu, h-plane xcT [n][c]
            if (row < M) {
              v += bias[col];
              v = fmaxf(v, 0.f);
              P0[bz * sP + (long)row * 512 + col] = f2bf(v);
            }
          } else if (MODE == 1) {  // QK: h planes, [n][c] coalesced
            if (row < M) {
              v += bias[col];
              const unsigned short h = f2bf(v);
              const int sc = col & 511;
              if (cb < 512)
                P0[bz * sP + (long)row * 512 + sc] = h;
              else
                R0[bz * sR + (long)row * 512 + sc] = h;
            }
          } else if (MODE == 2) {  // S: bf16 [row][1600]
            if (row < M && col < N)
              P0[bz * sP + (long)row * 1600 + col] = f2bf(v * alpha);
          } else if (MODE == 6) {  // V-direct: bf16 [c=row][n=col], bias by row
            if (col < N)
              V0[bz * sV + (long)row * 1600 + col] = f2bf(v + bias[row]);
          } else {  // MODE 3, OUT: += residual (xc_cn bf16, coalesced)
            if (col < N) {
              v += bf2f(xcn[bz * sXcn + (long)row * 1600 + col]);
              outF[bz * sOutF + (long)row * 1600 + col] = v;
            }
          }
        }
    }
}

// x [B][C][N] f32 -> xT planes [B][N][C] bf16 h/m
__global__ __launch_bounds__(256) void transpose_split_x(
    const float* __restrict__ x, unsigned short* __restrict__ X0,
    unsigned short* __restrict__ X1)
{
  __shared__ float t[32][33];
  const int bz = blockIdx.z;
  const int n0 = blockIdx.x * 32, c0 = blockIdx.y * 32;
  const int tx = threadIdx.x & 31, ty = threadIdx.x >> 5;
  const float* xb = x + (long)bz * 512 * 1600;
#pragma unroll
  for (int k = 0; k < 4; k++)
    t[ty + k * 8][tx] = xb[(long)(c0 + ty + k * 8) * 1600 + n0 + tx];
  __syncthreads();
  const long ob = (long)bz * 1600 * 512;
#pragma unroll
  for (int k = 0; k < 4; k++) {
    const float v = t[tx][ty + k * 8];
    const unsigned short h = f2bf(v);
    const unsigned short m_ = f2bf(v - bf2f(h));
    const long o = ob + (long)(n0 + ty + k * 8) * 512 + c0 + tx;
    X0[o] = h; X1[o] = m_;
  }
}

// xcT h-plane [n][c] -> xc_cn bf16 [c][n] (residual; precision uncritical)
__global__ __launch_bounds__(256) void transpose_xc(
    const unsigned short* __restrict__ xcTh, unsigned short* __restrict__ xccn)
{
  __shared__ unsigned short tc[32][33];
  const int bz = blockIdx.z;
  const int n0 = blockIdx.x * 32, c0 = blockIdx.y * 32;
  const int tx = threadIdx.x & 31, ty = threadIdx.x >> 5;
  const long ib = (long)bz * 819200L;
#pragma unroll
  for (int k = 0; k < 4; k++) {
    const int rr = ty + k * 8;
    tc[rr][tx] = xcTh[ib + (long)(n0 + rr) * 512 + c0 + tx];
  }
  __syncthreads();
#pragma unroll
  for (int k = 0; k < 4; k++) {
    const int rr = ty + k * 8;
    xccn[ib + (long)(c0 + rr) * 1600 + n0 + tx] = tc[tx][rr];
  }
}

__global__ __launch_bounds__(256) void split2_mat(
    const float* __restrict__ W, unsigned short* __restrict__ H,
    unsigned short* __restrict__ Mp, int n)
{
  const int i = blockIdx.x * 256 + threadIdx.x;
  if (i < n) {
    const float v = W[i];
    const unsigned short h = f2bf(v);
    H[i] = h; Mp[i] = f2bf(v - bf2f(h));
  }
}

// batched: bz selects (A,B) pair; W' = A @ B, h-plane only at rowoff = bz*512
__global__ __launch_bounds__(256) void combine_gemm3(
    const float* __restrict__ Aq, const float* __restrict__ Bq,
    const float* __restrict__ Ak, const float* __restrict__ Bk,
    const float* __restrict__ Av, const float* __restrict__ Bv,
    unsigned short* __restrict__ H)
{
  __shared__ float As[16][68];
  __shared__ float Bs[16][68];
  const int tid = threadIdx.x;
  const int bz = blockIdx.z;
  const float* A = (bz == 0) ? Aq : (bz == 1) ? Ak : Av;
  const float* B = (bz == 0) ? Bq : (bz == 1) ? Bk : Bv;
  const int rowoff = bz * 512;
  const int m0 = blockIdx.y * 64, n0 = blockIdx.x * 64;
  const int tx = tid & 15, ty = tid >> 4;
  float acc[4][4];
#pragma unroll
  for (int i = 0; i < 4; i++)
#pragma unroll
    for (int j = 0; j < 4; j++) acc[i][j] = 0.f;
  for (int k0 = 0; k0 < 512; k0 += 16) {
    {
      const int cA = tid & 15, r0 = tid >> 4;
#pragma unroll
      for (int l = 0; l < 4; l++)
        As[cA][r0 + 16 * l] = A[(long)(m0 + r0 + 16 * l) * 512 + (k0 + cA)];
      const int c2 = tid & 63, r2 = tid >> 6;
#pragma unroll
      for (int l = 0; l < 4; l++)
        Bs[r2 + 4 * l][c2] = B[(long)(k0 + r2 + 4 * l) * 512 + (n0 + c2)];
    }
    __syncthreads();
#pragma unroll
    for (int kk = 0; kk < 16; kk++) {
      float a[4], b[4];
#pragma unroll
      for (int i = 0; i < 4; i++) a[i] = As[kk][ty * 4 + i];
#pragma unroll
      for (int j = 0; j < 4; j++) b[j] = Bs[kk][tx * 4 + j];
#pragma unroll
      for (int i = 0; i < 4; i++)
#pragma unroll
        for (int j = 0; j < 4; j++) acc[i][j] = fmaf(a[i], b[j], acc[i][j]);
    }
    __syncthreads();
  }
#pragma unroll
  for (int i = 0; i < 4; i++) {
    const int m = rowoff + m0 + ty * 4 + i;
#pragma unroll
    for (int j = 0; j < 4; j++) {
      const int n = n0 + tx * 4 + j;
      H[(long)m * 512 + n] = f2bf(acc[i][j]);
    }
  }
}

// batched: bz selects (W2,b1,b2); bout offset bz*512
__global__ __launch_bounds__(256) void bias_combine3(
    const float* __restrict__ W2q, const float* __restrict__ b1q, const float* __restrict__ b2q,
    const float* __restrict__ W2k, const float* __restrict__ b1k, const float* __restrict__ b2k,
    const float* __restrict__ W2v, const float* __restrict__ b1v, const float* __restrict__ b2v,
    float* __restrict__ bout)
{
  const int bz = blockIdx.z;
  const float* W2 = (bz == 0) ? W2q : (bz == 1) ? W2k : W2v;
  const float* b1 = (bz == 0) ? b1q : (bz == 1) ? b1k : b1v;
  const float* b2 = (bz == 0) ? b2q : (bz == 1) ? b2k : b2v;
  const int o = blockIdx.x * 256 + threadIdx.x;
  if (o < 512) {
    float acc = b2[o];
    for (int t = 0; t < 512; t++) acc = fmaf(W2[(long)o * 512 + t], b1[t], acc);
    bout[bz * 512 + o] = acc;
  }
}

#define NROW 1600
#define NB 1024

// softmax + rank mask; reads S row (bf16), writes w = attn*mask bf16 in place.
// r15 version (empirical best 88.7us): two-exp, v-based linear bins over
// [0,rmax], scalar strided loads (conflict-free), no wmask; 5 barriers,
// 17.8 KB LDS -> 8 blocks/CU.
__global__ __launch_bounds__(256) void rowproc(unsigned short* __restrict__ S)
{
  __shared__ float sm[NROW];
  __shared__ unsigned short gidx[NROW];
  __shared__ int hist[NB];
  __shared__ int Rb[NB];
  __shared__ float redf[8];
  __shared__ int wtot[4];

  const int tid = threadIdx.x;
  const int lane = tid & 63, wid = tid >> 6;
  unsigned short* wrow = S + (long)blockIdx.x * NROW;

  // ---- load + per-wave max; zero hist
  float lmax = -3.4e38f;
  for (int i = tid; i < NROW; i += 256) {
    const float v = bf2f(wrow[i]);
    sm[i] = v;
    lmax = fmaxf(lmax, v);
  }
#pragma unroll
  for (int j = 0; j < NB / 256; j++) hist[tid + 256 * j] = 0;
#pragma unroll
  for (int d = 32; d; d >>= 1) lmax = fmaxf(lmax, __shfl_xor(lmax, d, 64));
  if (lane == 0) redf[wid] = lmax;
  __syncthreads();  // B1
  const float rmax = fmaxf(fmaxf(redf[0], redf[1]), fmaxf(redf[2], redf[3]));
  const float bsc = (rmax > 0.f) ? (float)NB * (1.f - 1e-6f) / rmax : 0.f;

  // ---- expsum + histogram of positives
  float lsum = 0.f;
  for (int i = tid; i < NROW; i += 256) {
    const float v = sm[i];
    lsum += __expf(v - rmax);
    if (v >= 0.f) {
      const int b = min(NB - 1, (int)(v * bsc));
      atomicAdd(&hist[b], 1);
    }
  }
#pragma unroll
  for (int d = 32; d; d >>= 1) lsum += __shfl_xor(lsum, d, 64);
  if (lane == 0) redf[4 + wid] = lsum;
  __syncthreads();  // B2 (hist also complete)
  const float Z = redf[4] + redf[5] + redf[6] + redf[7];
  const float invZ = 1.f / Z;

  // ---- suffix scan: thread owns bins 4t..4t+3; rank base = #elems in bins > b
  const int h0 = hist[4 * tid], h1 = hist[4 * tid + 1];
  const int h2 = hist[4 * tid + 2], h3 = hist[4 * tid + 3];
  const int loc = h0 + h1 + h2 + h3;
  int suf = loc;
#pragma unroll
  for (int d = 1; d < 64; d <<= 1) {
    const int o = __shfl_down(suf, d, 64);
    if (lane + d < 64) suf += o;
  }
  if (lane == 0) wtot[wid] = suf;
  __syncthreads();  // B3
  int above = 0;
#pragma unroll
  for (int w2 = 0; w2 < 4; w2++)
    if (w2 > wid) above += wtot[w2];
  const int P = wtot[0] + wtot[1] + wtot[2] + wtot[3];
  const int hiAll = (suf - loc) + above;
  Rb[4 * tid + 3] = hiAll;
  Rb[4 * tid + 2] = hiAll + h3;
  Rb[4 * tid + 1] = hiAll + h3 + h2;
  Rb[4 * tid + 0] = hiAll + h3 + h2 + h1;
  __syncthreads();  // B4

  // ---- scatter positives into bin groups; write negatives (mask=1) directly
  for (int i = tid; i < NROW; i += 256) {
    const float v = sm[i];
    if (v >= 0.f) {
      const int b = min(NB - 1, (int)(v * bsc));
      gidx[atomicAdd(&Rb[b], 1)] = (unsigned short)i;
    } else {
      wrow[i] = f2bf(__expf(v - rmax) * invZ);
    }
  }
  __syncthreads();  // B5

  // ---- within-bucket exact stable descending rank; write positives
  for (int p = tid; p < P; p += 256) {
    const int ip = gidx[p];
    const float vp = sm[ip];
    const int b = min(NB - 1, (int)(vp * bsc));
    const int end = Rb[b];
    const int start = end - hist[b];
    int cnt = 0;
    for (int qq = start; qq < end; qq++) {
      const int iq = gidx[qq];
      const float vq = sm[iq];
      cnt += (int)((vq > vp) || ((vq == vp) && (iq < ip)));
    }
    const float r1 = (float)(start + cnt + 1);
    wrow[ip] = f2bf(__expf(vp - rmax) * invZ * (r1 * r1 * r1));
  }
}

extern "C" void kernel_launch(void* const* d_in, const int* in_sizes, int n_in,
                              void* d_out, int out_size, void* d_ws, size_t ws_size,
                              hipStream_t stream)
{
  const float scale = 0.04419417382415922f;  // 1/sqrt(512)
  const long sCN = 819200L;                  // 512*1600
  const long sNN = 2560000L;                 // 1600*1600
  const long ePlane = 8L * sCN;              // elems per bf16 plane (batched)

  const float* x   = (const float*)d_in[0];
  const float* Wc  = (const float*)d_in[1];
  const float* bc  = (const float*)d_in[2];
  const float* Wq1 = (const float*)d_in[3];
  const float* bq1 = (const float*)d_in[4];
  const float* Wq2 = (const float*)d_in[5];
  const float* bq2 = (const float*)d_in[6];
  const float* Wk1 = (const float*)d_in[7];
  const float* bk1 = (const float*)d_in[8];
  const float* Wk2 = (const float*)d_in[9];
  const float* bk2 = (const float*)d_in[10];
  const float* Wv1 = (const float*)d_in[11];
  const float* bv1 = (const float*)d_in[12];
  const float* Wv2 = (const float*)d_in[13];
  const float* bv2 = (const float*)d_in[14];
  float* out = (float*)d_out;

  char* p = (char*)d_ws;
  auto carve = [&](size_t bytes) { char* r = p; p += (bytes + 255) & ~255UL; return r; };

  // S bf16 [B][1600][1600]; also hosts xT planes early, w plane (in place) late
  unsigned short* Sbf = (unsigned short*)carve(8L * sNN * 2);
  unsigned short* Xh = Sbf;
  unsigned short* Xm = Xh + ePlane;
  unsigned short* xcTh = (unsigned short*)carve(ePlane * 2);
  unsigned short* Qh = (unsigned short*)carve(ePlane * 2);
  unsigned short* Kh = (unsigned short*)carve(ePlane * 2);
  unsigned short* Vh = (unsigned short*)carve(ePlane * 2);
  unsigned short* xc_cn = (unsigned short*)carve(ePlane * 2);
  unsigned short* Wch = (unsigned short*)carve(512L * 512 * 2);
  unsigned short* Wcm = (unsigned short*)carve(512L * 512 * 2);
  unsigned short* Wh = (unsigned short*)carve(1536L * 512 * 2);
  float* bqkv = (float*)carve(1536L * 4);

  // prep: x transpose+split, Wc split, combined weights/biases (batched)
  transpose_split_x<<<dim3(50, 16, 8), 256, 0, stream>>>(x, Xh, Xm);
  split2_mat<<<dim3(1024), 256, 0, stream>>>(Wc, Wch, Wcm, 512 * 512);
  combine_gemm3<<<dim3(8, 8, 3), 256, 0, stream>>>(Wq2, Wq1, Wk2, Wk1, Wv2, Wv1, Wh);
  bias_combine3<<<dim3(2, 1, 3), 256, 0, stream>>>(Wq2, bq1, bq2, Wk2, bk1, bk2,
                                                   Wv2, bv1, bv2, bqkv);

  // xc = relu(xT . Wc^T + bc): [1600][512] -> xcT h-plane (3-product accuracy)
  mfma_gemm<0, 3><<<dim3(4 * 13 * 8), 256, 0, stream>>>(
      Xh, Xm, Wch, Wcm, 4, 13, 1600, 512, 512, 512, 512, sCN, 0L, bc, 1.f,
      nullptr, 0L, xcTh, sCN, nullptr, 0L, nullptr, 0L, nullptr, 0L);

  // QK: [1600][1024], 1-plane x 1-product (TK=64); Q,K h-planes [n][c]
  mfma_gemm<1, 1><<<dim3(8 * 13 * 8), 256, 0, stream>>>(
      xcTh, nullptr, Wh, nullptr, 8, 13, 1600, 1024, 512, 512, 512, sCN, 0L,
      bqkv, 1.f,
      nullptr, 0L, Qh, sCN, Kh, sCN, nullptr, 0L, nullptr, 0L);

  // V direct [c][n]: A=Wv (rows=c), B=xcTh (rows=n); bias by row (TK=64)
  mfma_gemm<6, 1><<<dim3(13 * 4 * 8), 256, 0, stream>>>(
      Wh + 1024L * 512, nullptr, xcTh, nullptr, 13, 4, 512, 1600, 512, 512, 512,
      0L, sCN, bqkv + 1024, 1.f,
      nullptr, 0L, nullptr, 0L, nullptr, 0L, Vh, sCN, nullptr, 0L);

  // xc residual -> bf16 [c][n]
  transpose_xc<<<dim3(50, 16, 8), 256, 0, stream>>>(xcTh, xc_cn);

  // S = scale * Qh . Kh^T : [1600][1600] bf16 (1-plane, TK=64)
  mfma_gemm<2, 1><<<dim3(13 * 13 * 8), 256, 0, stream>>>(
      Qh, nullptr, Kh, nullptr, 13, 13, 1600, 1600, 512, 512, 512, sCN, sCN,
      nullptr, scale,
      nullptr, 0L, Sbf, sNN, nullptr, 0L, nullptr, 0L, nullptr, 0L);

  // softmax + rank mask; overwrites S rows with w bf16
  rowproc<<<dim3(12800), 256, 0, stream>>>(Sbf);

  // out = V . w^T + xc : [512][1600] fp32 -> d_out (TK=64)
  mfma_gemm<3, 1><<<dim3(13 * 4 * 8), 256, 0, stream>>>(
      Vh, nullptr, Sbf, nullptr,
      13, 4, 512, 1600, 1600, 1600, 1600, sCN, sNN, nullptr, 1.f,
      out, sCN, nullptr, 0L, nullptr, 0L, nullptr, 0L, xc_cn, sCN);
}

// Round 21
// 301.113 us; speedup vs baseline: 2.0936x; 2.0936x over previous
//
#include <hip/hip_runtime.h>
#include <math.h>

typedef short short8 __attribute__((ext_vector_type(8)));
typedef float f32x16 __attribute__((ext_vector_type(16)));

__device__ __forceinline__ unsigned short f2bf(float f) {
  unsigned u = __float_as_uint(f);
  unsigned r = u + 0x7fffu + ((u >> 16) & 1u);
  return (unsigned short)(r >> 16);
}
__device__ __forceinline__ float bf2f(unsigned short s) {
  return __uint_as_float(((unsigned)s) << 16);
}
__device__ __forceinline__ void gload_lds16(const void* g, void* l) {
  __builtin_amdgcn_global_load_lds(
      (const __attribute__((address_space(1))) unsigned int*)g,
      (__attribute__((address_space(3))) unsigned int*)l, 16, 0, 0);
}

#define TM 128
#define TN 128
#define GH 7  // y-tiles grouped per rasterization column (L2 locality)

// NT MFMA GEMM. NPROD=3: 2-plane split, TK=32. NPROD=1: 1-plane, TK=64
// (32KB LDS, 32 MFMA per barrier). launch_bounds(256,4): 4 blocks/CU --
// NOTE (r20 post-mortem): (256,5) forces VGPR<=48 -> acc[2][2] spills to
// scratch (234MB writes, MfmaUtil 6.6%). Keep 4.
// 1D grid = GX*GY*GZ blocks (divisible by 8), XCD-chunked + grouped raster.
// MODE: 0=XC(h only) 1=QK(h only) 2=S(bf16) 3=OUT(+residual) 6=V-direct[c][n]
template<int MODE, int NPROD>
__global__ __launch_bounds__(256, 4) void mfma_gemm(
    const unsigned short* __restrict__ A0, const unsigned short* __restrict__ A1,
    const unsigned short* __restrict__ B0, const unsigned short* __restrict__ B1,
    int GX, int GY,
    int M, int N, int K, int ldA, int ldB, long sA, long sB,
    const float* __restrict__ bias, float alpha,
    float* __restrict__ outF, long sOutF,
    unsigned short* __restrict__ P0, long sP,
    unsigned short* __restrict__ R0, long sR,
    unsigned short* __restrict__ V0, long sV,
    const unsigned short* __restrict__ xcn, long sXcn)
{
  constexpr int NPL = (NPROD == 3) ? 2 : 1;
  constexpr int TKe = (NPROD == 1) ? 64 : 32;  // K-step
  constexpr int KK = TKe / 16;                 // MFMA sub-steps
  constexpr int NISS = TKe / 16;               // staging issues per matrix
  constexpr int SLOTS = TKe / 8;               // 16B slots per row
  __shared__ __align__(16) unsigned short As[NPL][128 * TKe];
  __shared__ __align__(16) unsigned short Bs[NPL][128 * TKe];

  const int tid = threadIdx.x;

  // ---- XCD-chunked bijective remap (total % 8 == 0) + grouped raster decode
  const int total = GX * GY * ((int)gridDim.x / (GX * GY));
  const int q = total >> 3;
  const int wg = blockIdx.x;
  const int c = (wg & 7) * q + (wg >> 3);
  const int pb = GX * GY;
  const int bz = c / pb;
  int r = c - bz * pb;
  const int gy = r / (GH * GX);
  int rr = r - gy * (GH * GX);
  const int hh = min(GH, GY - gy * GH);
  const int xt = rr / hh;
  const int yt = gy * GH + (rr - xt * hh);

  const int m0 = yt * TM, n0 = xt * TN;
  const int lane = tid & 63, w = tid >> 6;
  const int wm = w >> 1, wn = w & 1;
  const int g = lane >> 5, lr = lane & 31;

  // staging: issue i covers rows i*(256/SLOTS) + tid/SLOTS, slot tid%SLOTS;
  // source pre-swizzled so LDS slot s of row r holds k-chunk s ^ swz(r)
  const int strow = tid / SLOTS, stslot = tid % SLOTS;
  long aoff[NISS], boff[NISS];
#pragma unroll
  for (int i = 0; i < NISS; i++) {
    const int rw = i * (256 / SLOTS) + strow;
    const int sw = (TKe == 64) ? (stslot ^ (rw & 7)) : (stslot ^ ((rw >> 1) & 3));
    aoff[i] = (long)min(m0 + rw, M - 1) * ldA + sw * 8;
    boff[i] = (long)min(n0 + rw, N - 1) * ldB + sw * 8;
  }
  const unsigned short* Ap[2];
  const unsigned short* Bp[2];
  Ap[0] = A0 + bz * sA;
  Bp[0] = B0 + bz * sB;
  Ap[1] = (NPL == 2) ? A1 + bz * sA : Ap[0];
  Bp[1] = (NPL == 2) ? B1 + bz * sB : Bp[0];

  f32x16 acc[2][2];
#pragma unroll
  for (int i = 0; i < 2; i++)
#pragma unroll
    for (int j = 0; j < 2; j++)
#pragma unroll
      for (int e = 0; e < 16; e++) acc[i][j][e] = 0.f;

  const int NT = K / TKe;

  for (int kt = 0; kt < NT; kt++) {
    const long k0 = (long)kt * TKe;
    if (kt) __syncthreads();  // previous compute done before overwrite
#pragma unroll
    for (int p = 0; p < NPL; p++)
#pragma unroll
      for (int i = 0; i < NISS; i++) {
        gload_lds16(Ap[p] + aoff[i] + k0, (char*)&As[p][0] + i * 4096 + tid * 16);
        gload_lds16(Bp[p] + boff[i] + k0, (char*)&Bs[p][0] + i * 4096 + tid * 16);
      }
    __syncthreads();  // drain staging; other resident blocks compute meanwhile

#pragma unroll
    for (int kk = 0; kk < KK; kk++) {
      short8 af[2][NPL], bf[2][NPL];
#pragma unroll
      for (int i = 0; i < 2; i++) {
        const int rowa = wm * 64 + i * 32 + lr;
        const int sla = (TKe == 64) ? (((kk * 2 + g) ^ (rowa & 7)) * 8)
                                    : (((kk * 2 + g) ^ ((rowa >> 1) & 3)) * 8);
#pragma unroll
        for (int p = 0; p < NPL; p++)
          af[i][p] = *(const short8*)&As[p][rowa * TKe + sla];
        const int rowb = wn * 64 + i * 32 + lr;
        const int slb = (TKe == 64) ? (((kk * 2 + g) ^ (rowb & 7)) * 8)
                                    : (((kk * 2 + g) ^ ((rowb >> 1) & 3)) * 8);
#pragma unroll
        for (int p = 0; p < NPL; p++)
          bf[i][p] = *(const short8*)&Bs[p][rowb * TKe + slb];
      }
      __builtin_amdgcn_s_setprio(1);
#pragma unroll
      for (int i = 0; i < 2; i++)
#pragma unroll
        for (int j = 0; j < 2; j++) {
          acc[i][j] = __builtin_amdgcn_mfma_f32_32x32x16_bf16(af[i][0], bf[j][0], acc[i][j], 0, 0, 0);
          if (NPROD == 3) {
            acc[i][j] = __builtin_amdgcn_mfma_f32_32x32x16_bf16(af[i][0], bf[j][1], acc[i][j], 0, 0, 0);
            acc[i][j] = __builtin_amdgcn_mfma_f32_32x32x16_bf16(af[i][1], bf[j][0], acc[i][j], 0, 0, 0);
          }
        }
      __builtin_amdgcn_s_setprio(0);
    }
  }

  // epilogue: row = m0+wm*64+i*32 + rq*8 + g*4 + t ; col = n0+wn*64+j*32+lr
#pragma unroll
  for (int i = 0; i < 2; i++)
#pragma unroll
    for (int j = 0; j < 2; j++) {
      const int cb = n0 + wn * 64 + j * 32;
      const int col = cb + lr;
#pragma unroll
      for (int rq = 0; rq < 4; rq++)
#pragma unroll
        for (int t = 0; t < 4; t++) {
          const int reg = rq * 4 + t;
          const int row = m0 + wm * 64 + i * 32 + rq * 8 + g * 4 + t;
          float v = acc[i][j][reg];
          if (MODE == 0) {  // XC: relu, h-plane xcT [n][c]
            if (row < M) {
              v += bias[col];
              v = fmaxf(v, 0.f);
              P0[bz * sP + (long)row * 512 + col] = f2bf(v);
            }
          } else if (MODE == 1) {  // QK: h planes, [n][c] coalesced
            if (row < M) {
              v += bias[col];
              const unsigned short h = f2bf(v);
              const int sc = col & 511;
              if (cb < 512)
                P0[bz * sP + (long)row * 512 + sc] = h;
              else
                R0[bz * sR + (long)row * 512 + sc] = h;
            }
          } else if (MODE == 2) {  // S: bf16 [row][1600]
            if (row < M && col < N)
              P0[bz * sP + (long)row * 1600 + col] = f2bf(v * alpha);
          } else if (MODE == 6) {  // V-direct: bf16 [c=row][n=col], bias by row
            if (col < N)
              V0[bz * sV + (long)row * 1600 + col] = f2bf(v + bias[row]);
          } else {  // MODE 3, OUT: += residual (xc_cn bf16, coalesced)
            if (col < N) {
              v += bf2f(xcn[bz * sXcn + (long)row * 1600 + col]);
              outF[bz * sOutF + (long)row * 1600 + col] = v;
            }
          }
        }
    }
}

// x [B][C][N] f32 -> xT planes [B][N][C] bf16 h/m
__global__ __launch_bounds__(256) void transpose_split_x(
    const float* __restrict__ x, unsigned short* __restrict__ X0,
    unsigned short* __restrict__ X1)
{
  __shared__ float t[32][33];
  const int bz = blockIdx.z;
  const int n0 = blockIdx.x * 32, c0 = blockIdx.y * 32;
  const int tx = threadIdx.x & 31, ty = threadIdx.x >> 5;
  const float* xb = x + (long)bz * 512 * 1600;
#pragma unroll
  for (int k = 0; k < 4; k++)
    t[ty + k * 8][tx] = xb[(long)(c0 + ty + k * 8) * 1600 + n0 + tx];
  __syncthreads();
  const long ob = (long)bz * 1600 * 512;
#pragma unroll
  for (int k = 0; k < 4; k++) {
    const float v = t[tx][ty + k * 8];
    const unsigned short h = f2bf(v);
    const unsigned short m_ = f2bf(v - bf2f(h));
    const long o = ob + (long)(n0 + ty + k * 8) * 512 + c0 + tx;
    X0[o] = h; X1[o] = m_;
  }
}

// xcT h-plane [n][c] -> xc_cn bf16 [c][n] (residual; precision uncritical)
__global__ __launch_bounds__(256) void transpose_xc(
    const unsigned short* __restrict__ xcTh, unsigned short* __restrict__ xccn)
{
  __shared__ unsigned short tc[32][33];
  const int bz = blockIdx.z;
  const int n0 = blockIdx.x * 32, c0 = blockIdx.y * 32;
  const int tx = threadIdx.x & 31, ty = threadIdx.x >> 5;
  const long ib = (long)bz * 819200L;
#pragma unroll
  for (int k = 0; k < 4; k++) {
    const int rr = ty + k * 8;
    tc[rr][tx] = xcTh[ib + (long)(n0 + rr) * 512 + c0 + tx];
  }
  __syncthreads();
#pragma unroll
  for (int k = 0; k < 4; k++) {
    const int rr = ty + k * 8;
    xccn[ib + (long)(c0 + rr) * 1600 + n0 + tx] = tc[tx][rr];
  }
}

__global__ __launch_bounds__(256) void split2_mat(
    const float* __restrict__ W, unsigned short* __restrict__ H,
    unsigned short* __restrict__ Mp, int n)
{
  const int i = blockIdx.x * 256 + threadIdx.x;
  if (i < n) {
    const float v = W[i];
    const unsigned short h = f2bf(v);
    H[i] = h; Mp[i] = f2bf(v - bf2f(h));
  }
}

// batched: bz selects (A,B) pair; W' = A @ B, h-plane only at rowoff = bz*512
__global__ __launch_bounds__(256) void combine_gemm3(
    const float* __restrict__ Aq, const float* __restrict__ Bq,
    const float* __restrict__ Ak, const float* __restrict__ Bk,
    const float* __restrict__ Av, const float* __restrict__ Bv,
    unsigned short* __restrict__ H)
{
  __shared__ float As[16][68];
  __shared__ float Bs[16][68];
  const int tid = threadIdx.x;
  const int bz = blockIdx.z;
  const float* A = (bz == 0) ? Aq : (bz == 1) ? Ak : Av;
  const float* B = (bz == 0) ? Bq : (bz == 1) ? Bk : Bv;
  const int rowoff = bz * 512;
  const int m0 = blockIdx.y * 64, n0 = blockIdx.x * 64;
  const int tx = tid & 15, ty = tid >> 4;
  float acc[4][4];
#pragma unroll
  for (int i = 0; i < 4; i++)
#pragma unroll
    for (int j = 0; j < 4; j++) acc[i][j] = 0.f;
  for (int k0 = 0; k0 < 512; k0 += 16) {
    {
      const int cA = tid & 15, r0 = tid >> 4;
#pragma unroll
      for (int l = 0; l < 4; l++)
        As[cA][r0 + 16 * l] = A[(long)(m0 + r0 + 16 * l) * 512 + (k0 + cA)];
      const int c2 = tid & 63, r2 = tid >> 6;
#pragma unroll
      for (int l = 0; l < 4; l++)
        Bs[r2 + 4 * l][c2] = B[(long)(k0 + r2 + 4 * l) * 512 + (n0 + c2)];
    }
    __syncthreads();
#pragma unroll
    for (int kk = 0; kk < 16; kk++) {
      float a[4], b[4];
#pragma unroll
      for (int i = 0; i < 4; i++) a[i] = As[kk][ty * 4 + i];
#pragma unroll
      for (int j = 0; j < 4; j++) b[j] = Bs[kk][tx * 4 + j];
#pragma unroll
      for (int i = 0; i < 4; i++)
#pragma unroll
        for (int j = 0; j < 4; j++) acc[i][j] = fmaf(a[i], b[j], acc[i][j]);
    }
    __syncthreads();
  }
#pragma unroll
  for (int i = 0; i < 4; i++) {
    const int m = rowoff + m0 + ty * 4 + i;
#pragma unroll
    for (int j = 0; j < 4; j++) {
      const int n = n0 + tx * 4 + j;
      H[(long)m * 512 + n] = f2bf(acc[i][j]);
    }
  }
}

// batched: bz selects (W2,b1,b2); bout offset bz*512
__global__ __launch_bounds__(256) void bias_combine3(
    const float* __restrict__ W2q, const float* __restrict__ b1q, const float* __restrict__ b2q,
    const float* __restrict__ W2k, const float* __restrict__ b1k, const float* __restrict__ b2k,
    const float* __restrict__ W2v, const float* __restrict__ b1v, const float* __restrict__ b2v,
    float* __restrict__ bout)
{
  const int bz = blockIdx.z;
  const float* W2 = (bz == 0) ? W2q : (bz == 1) ? W2k : W2v;
  const float* b1 = (bz == 0) ? b1q : (bz == 1) ? b1k : b1v;
  const float* b2 = (bz == 0) ? b2q : (bz == 1) ? b2k : b2v;
  const int o = blockIdx.x * 256 + threadIdx.x;
  if (o < 512) {
    float acc = b2[o];
    for (int t = 0; t < 512; t++) acc = fmaf(W2[(long)o * 512 + t], b1[t], acc);
    bout[bz * 512 + o] = acc;
  }
}

#define NROW 1600
#define NB 1024

// softmax + rank mask; reads S row (bf16), writes w = attn*mask bf16 in place.
// r15 version (empirical best 88.7us): two-exp, v-based linear bins over
// [0,rmax], scalar strided loads (conflict-free), no wmask; 5 barriers,
// 17.8 KB LDS -> 8 blocks/CU.
__global__ __launch_bounds__(256) void rowproc(unsigned short* __restrict__ S)
{
  __shared__ float sm[NROW];
  __shared__ unsigned short gidx[NROW];
  __shared__ int hist[NB];
  __shared__ int Rb[NB];
  __shared__ float redf[8];
  __shared__ int wtot[4];

  const int tid = threadIdx.x;
  const int lane = tid & 63, wid = tid >> 6;
  unsigned short* wrow = S + (long)blockIdx.x * NROW;

  // ---- load + per-wave max; zero hist
  float lmax = -3.4e38f;
  for (int i = tid; i < NROW; i += 256) {
    const float v = bf2f(wrow[i]);
    sm[i] = v;
    lmax = fmaxf(lmax, v);
  }
#pragma unroll
  for (int j = 0; j < NB / 256; j++) hist[tid + 256 * j] = 0;
#pragma unroll
  for (int d = 32; d; d >>= 1) lmax = fmaxf(lmax, __shfl_xor(lmax, d, 64));
  if (lane == 0) redf[wid] = lmax;
  __syncthreads();  // B1
  const float rmax = fmaxf(fmaxf(redf[0], redf[1]), fmaxf(redf[2], redf[3]));
  const float bsc = (rmax > 0.f) ? (float)NB * (1.f - 1e-6f) / rmax : 0.f;

  // ---- expsum + histogram of positives
  float lsum = 0.f;
  for (int i = tid; i < NROW; i += 256) {
    const float v = sm[i];
    lsum += __expf(v - rmax);
    if (v >= 0.f) {
      const int b = min(NB - 1, (int)(v * bsc));
      atomicAdd(&hist[b], 1);
    }
  }
#pragma unroll
  for (int d = 32; d; d >>= 1) lsum += __shfl_xor(lsum, d, 64);
  if (lane == 0) redf[4 + wid] = lsum;
  __syncthreads();  // B2 (hist also complete)
  const float Z = redf[4] + redf[5] + redf[6] + redf[7];
  const float invZ = 1.f / Z;

  // ---- suffix scan: thread owns bins 4t..4t+3; rank base = #elems in bins > b
  const int h0 = hist[4 * tid], h1 = hist[4 * tid + 1];
  const int h2 = hist[4 * tid + 2], h3 = hist[4 * tid + 3];
  const int loc = h0 + h1 + h2 + h3;
  int suf = loc;
#pragma unroll
  for (int d = 1; d < 64; d <<= 1) {
    const int o = __shfl_down(suf, d, 64);
    if (lane + d < 64) suf += o;
  }
  if (lane == 0) wtot[wid] = suf;
  __syncthreads();  // B3
  int above = 0;
#pragma unroll
  for (int w2 = 0; w2 < 4; w2++)
    if (w2 > wid) above += wtot[w2];
  const int P = wtot[0] + wtot[1] + wtot[2] + wtot[3];
  const int hiAll = (suf - loc) + above;
  Rb[4 * tid + 3] = hiAll;
  Rb[4 * tid + 2] = hiAll + h3;
  Rb[4 * tid + 1] = hiAll + h3 + h2;
  Rb[4 * tid + 0] = hiAll + h3 + h2 + h1;
  __syncthreads();  // B4

  // ---- scatter positives into bin groups; write negatives (mask=1) directly
  for (int i = tid; i < NROW; i += 256) {
    const float v = sm[i];
    if (v >= 0.f) {
      const int b = min(NB - 1, (int)(v * bsc));
      gidx[atomicAdd(&Rb[b], 1)] = (unsigned short)i;
    } else {
      wrow[i] = f2bf(__expf(v - rmax) * invZ);
    }
  }
  __syncthreads();  // B5

  // ---- within-bucket exact stable descending rank; write positives
  for (int p = tid; p < P; p += 256) {
    const int ip = gidx[p];
    const float vp = sm[ip];
    const int b = min(NB - 1, (int)(vp * bsc));
    const int end = Rb[b];
    const int start = end - hist[b];
    int cnt = 0;
    for (int qq = start; qq < end; qq++) {
      const int iq = gidx[qq];
      const float vq = sm[iq];
      cnt += (int)((vq > vp) || ((vq == vp) && (iq < ip)));
    }
    const float r1 = (float)(start + cnt + 1);
    wrow[ip] = f2bf(__expf(vp - rmax) * invZ * (r1 * r1 * r1));
  }
}

extern "C" void kernel_launch(void* const* d_in, const int* in_sizes, int n_in,
                              void* d_out, int out_size, void* d_ws, size_t ws_size,
                              hipStream_t stream)
{
  const float scale = 0.04419417382415922f;  // 1/sqrt(512)
  const long sCN = 819200L;                  // 512*1600
  const long sNN = 2560000L;                 // 1600*1600
  const long ePlane = 8L * sCN;              // elems per bf16 plane (batched)

  const float* x   = (const float*)d_in[0];
  const float* Wc  = (const float*)d_in[1];
  const float* bc  = (const float*)d_in[2];
  const float* Wq1 = (const float*)d_in[3];
  const float* bq1 = (const float*)d_in[4];
  const float* Wq2 = (const float*)d_in[5];
  const float* bq2 = (const float*)d_in[6];
  const float* Wk1 = (const float*)d_in[7];
  const float* bk1 = (const float*)d_in[8];
  const float* Wk2 = (const float*)d_in[9];
  const float* bk2 = (const float*)d_in[10];
  const float* Wv1 = (const float*)d_in[11];
  const float* bv1 = (const float*)d_in[12];
  const float* Wv2 = (const float*)d_in[13];
  const float* bv2 = (const float*)d_in[14];
  float* out = (float*)d_out;

  char* p = (char*)d_ws;
  auto carve = [&](size_t bytes) { char* r = p; p += (bytes + 255) & ~255UL; return r; };

  // S bf16 [B][1600][1600]; also hosts xT planes early, w plane (in place) late
  unsigned short* Sbf = (unsigned short*)carve(8L * sNN * 2);
  unsigned short* Xh = Sbf;
  unsigned short* Xm = Xh + ePlane;
  unsigned short* xcTh = (unsigned short*)carve(ePlane * 2);
  unsigned short* Qh = (unsigned short*)carve(ePlane * 2);
  unsigned short* Kh = (unsigned short*)carve(ePlane * 2);
  unsigned short* Vh = (unsigned short*)carve(ePlane * 2);
  unsigned short* xc_cn = (unsigned short*)carve(ePlane * 2);
  unsigned short* Wch = (unsigned short*)carve(512L * 512 * 2);
  unsigned short* Wcm = (unsigned short*)carve(512L * 512 * 2);
  unsigned short* Wh = (unsigned short*)carve(1536L * 512 * 2);
  float* bqkv = (float*)carve(1536L * 4);

  // prep: x transpose+split, Wc split, combined weights/biases (batched)
  transpose_split_x<<<dim3(50, 16, 8), 256, 0, stream>>>(x, Xh, Xm);
  split2_mat<<<dim3(1024), 256, 0, stream>>>(Wc, Wch, Wcm, 512 * 512);
  combine_gemm3<<<dim3(8, 8, 3), 256, 0, stream>>>(Wq2, Wq1, Wk2, Wk1, Wv2, Wv1, Wh);
  bias_combine3<<<dim3(2, 1, 3), 256, 0, stream>>>(Wq2, bq1, bq2, Wk2, bk1, bk2,
                                                   Wv2, bv1, bv2, bqkv);

  // xc = relu(xT . Wc^T + bc): [1600][512] -> xcT h-plane (3-product accuracy)
  mfma_gemm<0, 3><<<dim3(4 * 13 * 8), 256, 0, stream>>>(
      Xh, Xm, Wch, Wcm, 4, 13, 1600, 512, 512, 512, 512, sCN, 0L, bc, 1.f,
      nullptr, 0L, xcTh, sCN, nullptr, 0L, nullptr, 0L, nullptr, 0L);

  // QK: [1600][1024], 1-plane x 1-product (TK=64); Q,K h-planes [n][c]
  mfma_gemm<1, 1><<<dim3(8 * 13 * 8), 256, 0, stream>>>(
      xcTh, nullptr, Wh, nullptr, 8, 13, 1600, 1024, 512, 512, 512, sCN, 0L,
      bqkv, 1.f,
      nullptr, 0L, Qh, sCN, Kh, sCN, nullptr, 0L, nullptr, 0L);

  // V direct [c][n]: A=Wv (rows=c), B=xcTh (rows=n); bias by row (TK=64)
  mfma_gemm<6, 1><<<dim3(13 * 4 * 8), 256, 0, stream>>>(
      Wh + 1024L * 512, nullptr, xcTh, nullptr, 13, 4, 512, 1600, 512, 512, 512,
      0L, sCN, bqkv + 1024, 1.f,
      nullptr, 0L, nullptr, 0L, nullptr, 0L, Vh, sCN, nullptr, 0L);

  // xc residual -> bf16 [c][n]
  transpose_xc<<<dim3(50, 16, 8), 256, 0, stream>>>(xcTh, xc_cn);

  // S = scale * Qh . Kh^T : [1600][1600] bf16 (1-plane, TK=64)
  mfma_gemm<2, 1><<<dim3(13 * 13 * 8), 256, 0, stream>>>(
      Qh, nullptr, Kh, nullptr, 13, 13, 1600, 1600, 512, 512, 512, sCN, sCN,
      nullptr, scale,
      nullptr, 0L, Sbf, sNN, nullptr, 0L, nullptr, 0L, nullptr, 0L);

  // softmax + rank mask; overwrites S rows with w bf16
  rowproc<<<dim3(12800), 256, 0, stream>>>(Sbf);

  // out = V . w^T + xc : [512][1600] fp32 -> d_out (TK=64)
  mfma_gemm<3, 1><<<dim3(13 * 4 * 8), 256, 0, stream>>>(
      Vh, nullptr, Sbf, nullptr,
      13, 4, 512, 1600, 1600, 1600, 1600, sCN, sNN, nullptr, 1.f,
      out, sCN, nullptr, 0L, nullptr, 0L, nullptr, 0L, xc_cn, sCN);
}